// Round 9
// baseline (308.479 us; speedup 1.0000x reference)
//
#include <hip/hip_runtime.h>

// Bahdanau attention, MI355X. B=32, S=4096, D=U=512, fp32 in/out.
// R9 = R8 with the nontemporal builtin applied to ext_vector f32x4 pointers
//     (HIP_vector_type float4 is rejected by __builtin_nontemporal_load).
// R8: nontemporal values stream (don't evict W1f from L2), setprio dropped.
// R6: depth-1 ping-pong prefetch, 64 VGPR, no spills.
// R5 base: U-split acc (32 regs), fragment-linear LDS (0 conflicts).
#define NB 32
#define NS 4096
#define ND 512
#define NU 512

typedef __attribute__((ext_vector_type(8))) __bf16 bf16x8;
typedef __attribute__((ext_vector_type(8))) short short8;
typedef __attribute__((ext_vector_type(4))) float f32x4;

union Cvt8 { __bf16 h[8]; short8 s8; };

__device__ __forceinline__ float fast_tanh(float x) {
  float e = __expf(2.0f * x);
  return 1.0f - __fdividef(2.0f, e + 1.0f);
}

// ---- K0a: pack W1 (f32 [D][U]) -> bf16 MFMA B-fragment order ----
// W1f[ks][ct][lane][j]: k = ks*32 + (lane>>4)*8 + j, u = ct*16 + (lane&15)
__global__ void pack_w1_kernel(const float* __restrict__ W1, __bf16* __restrict__ W1f) {
  int idx = blockIdx.x * 256 + threadIdx.x;   // [16 ks][32 ct][64 lane]
  int l  = idx & 63;
  int ct = (idx >> 6) & 31;
  int ks = idx >> 11;
  int col   = ct * 16 + (l & 15);
  int kbase = ks * 32 + (l >> 4) * 8;
  Cvt8 u;
#pragma unroll
  for (int j = 0; j < 8; ++j) u.h[j] = (__bf16)W1[(size_t)(kbase + j) * NU + col];
  *reinterpret_cast<short8*>(W1f + (size_t)idx * 8) = u.s8;
}

// ---- K0b: pq[b][u] = query[b]@W2[:,u] + b2[u] + b1[u] ----
__global__ void proj_query_kernel(const float* __restrict__ query, const float* __restrict__ W2,
                                  const float* __restrict__ b2, const float* __restrict__ b1,
                                  float* __restrict__ pq) {
  int b = blockIdx.y;
  int u = blockIdx.x * 256 + threadIdx.x;
  const float* q = query + (size_t)b * ND;
  float acc = b2[u] + b1[u];
  for (int k = 0; k < ND; ++k) acc += q[k] * W2[(size_t)k * NU + u];
  pq[(size_t)b * NU + u] = acc;
}

// ---- K2: score[b][s] = sum_u tanh(values[b,s,:]@W1[:,u] + pq[b][u]) * V[u] ----
// One 64-row tile per block, 8 waves, fragment-linear LDS (see R5 comment).
__global__ __launch_bounds__(512, 4)
void score_kernel(const float* __restrict__ values, const __bf16* __restrict__ W1f,
                  const float* __restrict__ pq, const float* __restrict__ V,
                  float* __restrict__ scoreW) {
  __shared__ __align__(16) char ldsb[67584];  // 64KB tile + 2KB reduce buf
  float* sbuf = (float*)(ldsb + 65536);       // [8 waves][64 rows]

  int bid = blockIdx.x;                       // 2048 = 32 b * 64 tiles
  int b = bid >> 6;
  int s0 = (bid & 63) * 64;
  int tid = threadIdx.x;                      // 512
  int l = tid & 63;
  int w = tid >> 6;
  int lane_col = l & 15;
  int lane_k8  = l >> 4;

  // hoisted epilogue constants: 4 cols/thread = [nb][cf]
  float pqv[4], Vv[4];
#pragma unroll
  for (int nb = 0; nb < 2; ++nb)
#pragma unroll
    for (int cf = 0; cf < 2; ++cf) {
      int col = nb * 256 + w * 32 + cf * 16 + lane_col;
      pqv[nb * 2 + cf] = pq[(size_t)b * NU + col];
      Vv[nb * 2 + cf]  = V[col];
    }

  const float* vbase = values + ((size_t)b * NS + s0) * ND;

  // stage: 4096 16B chunks, 8 per thread. LDS linear; global decode per chunk.
  // Nontemporal: values is a one-shot stream; don't let it evict W1f from L2.
#pragma unroll
  for (int i = 0; i < 8; ++i) {
    int c  = i * 512 + tid;
    int t  = c >> 10;
    int kg = (c >> 6) & 15;
    int ln = c & 63;
    int s  = t * 16 + (ln & 15);
    int c8 = kg * 4 + (ln >> 4);
    const f32x4* p = reinterpret_cast<const f32x4*>(vbase + (size_t)s * ND + c8 * 8);
    f32x4 f0 = __builtin_nontemporal_load(p);
    f32x4 f1 = __builtin_nontemporal_load(p + 1);
    Cvt8 u;
    u.h[0] = (__bf16)f0.x; u.h[1] = (__bf16)f0.y; u.h[2] = (__bf16)f0.z; u.h[3] = (__bf16)f0.w;
    u.h[4] = (__bf16)f1.x; u.h[5] = (__bf16)f1.y; u.h[6] = (__bf16)f1.z; u.h[7] = (__bf16)f1.w;
    *reinterpret_cast<short8*>(ldsb + (size_t)c * 16) = u.s8;
  }
  __syncthreads();

  float partial[4][4];                        // [t][r], carried across nb
#pragma unroll
  for (int t = 0; t < 4; ++t)
#pragma unroll
    for (int r = 0; r < 4; ++r) partial[t][r] = 0.f;

#pragma unroll
  for (int nb = 0; nb < 2; ++nb) {
    f32x4 acc[4][2];
#pragma unroll
    for (int t = 0; t < 4; ++t)
#pragma unroll
      for (int cf = 0; cf < 2; ++cf) acc[t][cf] = (f32x4){0.f, 0.f, 0.f, 0.f};

    // B-frag base for ct0 = nb*16 + w*2 (element units)
    const __bf16* wp = W1f + ((size_t)(nb * 16 + w * 2) * 64 + l) * 8;

    // ping-pong prefetch: issue kg+1 loads before kg's MFMA cluster
    bf16x8 aa[2][4];
    bf16x8 bbb[2][2];
#pragma unroll
    for (int t = 0; t < 4; ++t)
      aa[0][t] = *reinterpret_cast<const bf16x8*>(ldsb + (((t * 16 + 0) * 64 + l) << 4));
#pragma unroll
    for (int cf = 0; cf < 2; ++cf)
      bbb[0][cf] = *reinterpret_cast<const bf16x8*>(wp + (size_t)0 * 16384 + cf * 512);

#pragma unroll
    for (int kg = 0; kg < 16; ++kg) {
      const int cur = kg & 1, nxt = cur ^ 1;
      if (kg < 15) {
#pragma unroll
        for (int cf = 0; cf < 2; ++cf)     // B first: longest latency
          bbb[nxt][cf] = *reinterpret_cast<const bf16x8*>(wp + (size_t)(kg + 1) * 16384 + cf * 512);
#pragma unroll
        for (int t = 0; t < 4; ++t)
          aa[nxt][t] = *reinterpret_cast<const bf16x8*>(ldsb + (((t * 16 + kg + 1) * 64 + l) << 4));
      }
#pragma unroll
      for (int cf = 0; cf < 2; ++cf)
#pragma unroll
        for (int t = 0; t < 4; ++t)
          acc[t][cf] = __builtin_amdgcn_mfma_f32_16x16x32_bf16(aa[cur][t], bbb[cur][cf], acc[t][cf], 0, 0, 0);
    }

    // fold this nb's cols into partial: tanh(proj + pq) * V
#pragma unroll
    for (int cf = 0; cf < 2; ++cf)
#pragma unroll
      for (int t = 0; t < 4; ++t)
#pragma unroll
        for (int r = 0; r < 4; ++r)
          partial[t][r] += fast_tanh(acc[t][cf][r] + pqv[nb * 2 + cf]) * Vv[nb * 2 + cf];
  }

  // reduce over the 16 lane_col lanes (cols), then across 8 waves via LDS
#pragma unroll
  for (int off = 1; off < 16; off <<= 1)
#pragma unroll
    for (int t = 0; t < 4; ++t)
#pragma unroll
      for (int r = 0; r < 4; ++r) partial[t][r] += __shfl_xor(partial[t][r], off);

  if (lane_col == 0) {
#pragma unroll
    for (int t = 0; t < 4; ++t)
#pragma unroll
      for (int r = 0; r < 4; ++r)
        sbuf[w * 64 + t * 16 + lane_k8 * 4 + r] = partial[t][r];
  }
  __syncthreads();
  if (tid < 64) {
    float sc = 0.f;
#pragma unroll
    for (int wv = 0; wv < 8; ++wv) sc += sbuf[wv * 64 + tid];
    scoreW[(size_t)b * NS + s0 + tid] = sc;   // bv omitted: softmax shift-invariant
  }
}

// ---- K3: softmax over S per batch -> attention weights (d_out tail) ----
__global__ void softmax_kernel(const float* __restrict__ scoreW, float* __restrict__ attn) {
  int b = blockIdx.x, tid = threadIdx.x;      // 256 threads
  __shared__ float sred[8];
  const float* sc = scoreW + (size_t)b * NS;
  float m = -3.0e38f;
  for (int s = tid; s < NS; s += 256) m = fmaxf(m, sc[s]);
#pragma unroll
  for (int off = 1; off < 64; off <<= 1) m = fmaxf(m, __shfl_xor(m, off));
  if ((tid & 63) == 0) sred[tid >> 6] = m;
  __syncthreads();
  m = fmaxf(fmaxf(sred[0], sred[1]), fmaxf(sred[2], sred[3]));
  float sum = 0.f;
  for (int s = tid; s < NS; s += 256) sum += __expf(sc[s] - m);
#pragma unroll
  for (int off = 1; off < 64; off <<= 1) sum += __shfl_xor(sum, off);
  if ((tid & 63) == 0) sred[4 + (tid >> 6)] = sum;
  __syncthreads();
  float inv = 1.f / (sred[4] + sred[5] + sred[6] + sred[7]);
  float* ab = attn + (size_t)b * NS;
  for (int s = tid; s < NS; s += 256) ab[s] = __expf(sc[s] - m) * inv;
}

// ---- K4: context partials over 256-row chunks (values nontemporal) ----
__global__ void context_partial_kernel(const float* __restrict__ values,
                                       const float* __restrict__ attn,
                                       float* __restrict__ ctxpart) {
  int blk = blockIdx.x;                       // 32 b * 16 chunks
  int b = blk >> 4, c = blk & 15;
  int tid = threadIdx.x;                      // 256
  int t2 = tid & 127;
  int sg = tid >> 7;
  const float* vb = values + ((size_t)b * NS + c * 256) * ND;
  const float* ab = attn + (size_t)b * NS + c * 256;
  f32x4 acc = {0.f, 0.f, 0.f, 0.f};
  for (int s = sg; s < 256; s += 2) {
    float wv = ab[s];
    f32x4 v = __builtin_nontemporal_load(reinterpret_cast<const f32x4*>(vb + (size_t)s * ND + t2 * 4));
    acc += v * wv;
  }
  __shared__ f32x4 red[128];
  if (sg == 1) red[t2] = acc;
  __syncthreads();
  if (sg == 0) {
    acc += red[t2];
    *reinterpret_cast<f32x4*>(ctxpart + (size_t)blk * ND + t2 * 4) = acc;
  }
}

// ---- K5: reduce chunk partials -> context_vector (d_out head) ----
__global__ void context_reduce_kernel(const float* __restrict__ ctxpart, float* __restrict__ ctx) {
  int b = blockIdx.x, tid = threadIdx.x;      // 128 threads * float4
  f32x4 acc = {0.f, 0.f, 0.f, 0.f};
  for (int c = 0; c < 16; ++c)
    acc += *reinterpret_cast<const f32x4*>(ctxpart + (size_t)(b * 16 + c) * ND + tid * 4);
  *reinterpret_cast<f32x4*>(ctx + (size_t)b * ND + tid * 4) = acc;
}

extern "C" void kernel_launch(void* const* d_in, const int* in_sizes, int n_in,
                              void* d_out, int out_size, void* d_ws, size_t ws_size,
                              hipStream_t stream) {
  const float* query  = (const float*)d_in[0];
  const float* values = (const float*)d_in[1];
  const float* W1     = (const float*)d_in[2];
  const float* b1     = (const float*)d_in[3];
  const float* W2     = (const float*)d_in[4];
  const float* b2     = (const float*)d_in[5];
  const float* V      = (const float*)d_in[6];
  // d_in[7] = bv: softmax-invariant, score not an output: dropped.

  float* ctx_out  = (float*)d_out;            // [32][512]
  float* attn_out = ctx_out + NB * ND;        // [32][4096]

  char* ws = (char*)d_ws;
  __bf16* W1f    = (__bf16*)ws;               // 512 KB
  float*  pq     = (float*)(ws + 524288);     // 64 KB
  float*  scoreW = (float*)(ws + 589824);     // 512 KB
  float*  ctxp   = (float*)(ws + 1114112);    // 1 MB

  hipLaunchKernelGGL(pack_w1_kernel,        dim3(128),     dim3(256), 0, stream, W1, W1f);
  hipLaunchKernelGGL(proj_query_kernel,     dim3(2, NB),   dim3(256), 0, stream, query, W2, b2, b1, pq);
  hipLaunchKernelGGL(score_kernel,          dim3(2048),    dim3(512), 0, stream, values, W1f, pq, V, scoreW);
  hipLaunchKernelGGL(softmax_kernel,        dim3(NB),      dim3(256), 0, stream, scoreW, attn_out);
  hipLaunchKernelGGL(context_partial_kernel,dim3(NB * 16), dim3(256), 0, stream, values, attn_out, ctxp);
  hipLaunchKernelGGL(context_reduce_kernel, dim3(NB),      dim3(128), 0, stream, ctxp, ctx_out);
}

// Round 10
// 285.592 us; speedup vs baseline: 1.0801x; 1.0801x over previous
//
#include <hip/hip_runtime.h>

// Bahdanau attention, MI355X. B=32, S=4096, D=U=512, fp32 in/out.
// R10: 128-row full-K tile (128KB LDS, 1 block/CU) -> W1f re-read traffic
//      halved (1.05GB -> 537MB). Discriminates latency-bound vs traffic-bound.
//      K-half-2 staging pipelined into nb0 kg0..7 (load-early/write-late, T14).
//      __launch_bounds__(512,2): 256-VGPR cap, spills impossible (R4/R7 lesson).
//      XCD-chunked bijective swizzle (1024%8==0). nt loads reverted (R9: nt
//      evicts ALL levels -> FETCH+WRITE exploded).
#define NB 32
#define NS 4096
#define ND 512
#define NU 512

typedef __attribute__((ext_vector_type(8))) __bf16 bf16x8;
typedef __attribute__((ext_vector_type(8))) short short8;
typedef __attribute__((ext_vector_type(4))) float f32x4;

union Cvt8 { __bf16 h[8]; short8 s8; };

__device__ __forceinline__ float fast_tanh(float x) {
  float e = __expf(2.0f * x);
  return 1.0f - __fdividef(2.0f, e + 1.0f);
}

// ---- K0a: pack W1 (f32 [D][U]) -> bf16 MFMA B-fragment order ----
// W1f[ks][ct][lane][j]: k = ks*32 + (lane>>4)*8 + j, u = ct*16 + (lane&15)
__global__ void pack_w1_kernel(const float* __restrict__ W1, __bf16* __restrict__ W1f) {
  int idx = blockIdx.x * 256 + threadIdx.x;   // [16 ks][32 ct][64 lane]
  int l  = idx & 63;
  int ct = (idx >> 6) & 31;
  int ks = idx >> 11;
  int col   = ct * 16 + (l & 15);
  int kbase = ks * 32 + (l >> 4) * 8;
  Cvt8 u;
#pragma unroll
  for (int j = 0; j < 8; ++j) u.h[j] = (__bf16)W1[(size_t)(kbase + j) * NU + col];
  *reinterpret_cast<short8*>(W1f + (size_t)idx * 8) = u.s8;
}

// ---- K0b: pq[b][u] = query[b]@W2[:,u] + b2[u] + b1[u] ----
__global__ void proj_query_kernel(const float* __restrict__ query, const float* __restrict__ W2,
                                  const float* __restrict__ b2, const float* __restrict__ b1,
                                  float* __restrict__ pq) {
  int b = blockIdx.y;
  int u = blockIdx.x * 256 + threadIdx.x;
  const float* q = query + (size_t)b * ND;
  float acc = b2[u] + b1[u];
  for (int k = 0; k < ND; ++k) acc += q[k] * W2[(size_t)k * NU + u];
  pq[(size_t)b * NU + u] = acc;
}

// ---- K2: score[b][s] = sum_u tanh(values[b,s,:]@W1[:,u] + pq[b][u]) * V[u] ----
// 128-row tile, 8 waves: wave w -> row-half h=w>>2 (64 rows), col-quarter
// cq=w&3 (64 cols per nb pass, 2 passes). Fragment-linear LDS: chunk
// c=(tg*16+kg)*64+lane at byte c*16 holds s=tg*16+(lane&15), k=kg*32+(lane>>4)*8+j.
// Even-i chunks (per-thread) = kg<8 (staged in prologue); odd-i = kg>=8
// (pipelined into nb0 kg0..7: load at kg, write at kg+1, barrier at kg8).
__global__ __launch_bounds__(512, 2)
void score_kernel(const float* __restrict__ values, const __bf16* __restrict__ W1f,
                  const float* __restrict__ pq, const float* __restrict__ V,
                  float* __restrict__ scoreW) {
  __shared__ __align__(16) char ldsb[133120]; // 128KB tile + 2KB reduce buf
  float* sbuf = (float*)(ldsb + 131072);      // [8 waves][64 rows]

  int bid0 = blockIdx.x;                      // 1024 = 32 b * 32 tiles
  int bid = (bid0 & 7) * 128 + (bid0 >> 3);   // XCD-chunked swizzle (bijective)
  int b = bid >> 5;
  int s0 = (bid & 31) * 128;
  int tid = threadIdx.x;                      // 512
  int l = tid & 63;
  int w = tid >> 6;
  int lane_col = l & 15;
  int lane_k8  = l >> 4;
  int cq = w & 3;                             // col-quarter
  int h  = w >> 2;                            // row-half

  // hoisted epilogue constants: [nb][cf]
  float pqv[8], Vv[8];
#pragma unroll
  for (int nb = 0; nb < 2; ++nb)
#pragma unroll
    for (int cf = 0; cf < 4; ++cf) {
      int col = nb * 256 + cq * 64 + cf * 16 + lane_col;
      pqv[nb * 4 + cf] = pq[(size_t)b * NU + col];
      Vv[nb * 4 + cf]  = V[col];
    }

  const float* vbase = values + ((size_t)b * NS + s0) * ND;

  // chunk decode: c = i*512 + tid; tg=c>>10, kg=(c>>6)&15, ln=c&63
  auto stage_load = [&](f32x4* s, int i) {
    int c = i * 512 + tid;
    int tg = c >> 10, kg = (c >> 6) & 15, ln = c & 63;
    int srow = tg * 16 + (ln & 15);
    int c8 = kg * 4 + (ln >> 4);
    const f32x4* p = reinterpret_cast<const f32x4*>(vbase + (size_t)srow * ND + c8 * 8);
    s[0] = p[0]; s[1] = p[1];
  };
  auto stage_write = [&](const f32x4* s, int i) {
    int c = i * 512 + tid;
    Cvt8 u;
    u.h[0] = (__bf16)s[0].x; u.h[1] = (__bf16)s[0].y; u.h[2] = (__bf16)s[0].z; u.h[3] = (__bf16)s[0].w;
    u.h[4] = (__bf16)s[1].x; u.h[5] = (__bf16)s[1].y; u.h[6] = (__bf16)s[1].z; u.h[7] = (__bf16)s[1].w;
    *reinterpret_cast<short8*>(ldsb + (size_t)c * 16) = u.s8;
  };

  // prologue: stage k-half1 (even-i chunks: i = 0,2,...,14)
  {
    f32x4 sA[2], sB[2];
#pragma unroll
    for (int ii = 0; ii < 4; ++ii) {
      stage_load(sA, ii * 4);
      stage_load(sB, ii * 4 + 2);
      stage_write(sA, ii * 4);
      stage_write(sB, ii * 4 + 2);
    }
  }
  __syncthreads();

  float partial[4][4];                        // [t][r], carried across nb
#pragma unroll
  for (int t = 0; t < 4; ++t)
#pragma unroll
    for (int r = 0; r < 4; ++r) partial[t][r] = 0.f;

  const int tgb = h * 4;                      // wave's first 16-row group

  // ---------------- nb = 0 (with k-half2 staging pipelined in) -------------
  {
    f32x4 acc[4][4];
#pragma unroll
    for (int t = 0; t < 4; ++t)
#pragma unroll
      for (int cf = 0; cf < 4; ++cf) acc[t][cf] = (f32x4){0.f, 0.f, 0.f, 0.f};

    const __bf16* wp = W1f + ((size_t)(cq * 4) * 64 + l) * 8;   // nb0 ct base
    bf16x8 bbb[2][4];
#pragma unroll
    for (int cf = 0; cf < 4; ++cf)
      bbb[0][cf] = *reinterpret_cast<const bf16x8*>(wp + (size_t)(cf) * 512);

    f32x4 stp[2][2];                          // staging ping-pong (odd chunks)
#pragma unroll
    for (int kg = 0; kg < 16; ++kg) {
      const int cur = kg & 1, nxt = cur ^ 1;
      if (kg >= 1 && kg <= 8) stage_write(stp[(kg - 1) & 1], 2 * (kg - 1) + 1);
      if (kg == 8) __syncthreads();           // k-half2 fully staged
      if (kg < 8) stage_load(stp[kg & 1], 2 * kg + 1);
      bf16x8 a[4];
#pragma unroll
      for (int t = 0; t < 4; ++t)
        a[t] = *reinterpret_cast<const bf16x8*>(ldsb + ((((tgb + t) * 16 + kg) * 64 + l) << 4));
      if (kg < 15) {
#pragma unroll
        for (int cf = 0; cf < 4; ++cf)
          bbb[nxt][cf] = *reinterpret_cast<const bf16x8*>(wp + (size_t)(kg + 1) * 16384 + cf * 512);
      }
#pragma unroll
      for (int cf = 0; cf < 4; ++cf)
#pragma unroll
        for (int t = 0; t < 4; ++t)
          acc[t][cf] = __builtin_amdgcn_mfma_f32_16x16x32_bf16(a[t], bbb[cur][cf], acc[t][cf], 0, 0, 0);
    }
#pragma unroll
    for (int cf = 0; cf < 4; ++cf)
#pragma unroll
      for (int t = 0; t < 4; ++t)
#pragma unroll
        for (int r = 0; r < 4; ++r)
          partial[t][r] += fast_tanh(acc[t][cf][r] + pqv[cf]) * Vv[cf];
  }

  // ---------------- nb = 1 (pure compute) ----------------------------------
  {
    f32x4 acc[4][4];
#pragma unroll
    for (int t = 0; t < 4; ++t)
#pragma unroll
      for (int cf = 0; cf < 4; ++cf) acc[t][cf] = (f32x4){0.f, 0.f, 0.f, 0.f};

    const __bf16* wp = W1f + ((size_t)(16 + cq * 4) * 64 + l) * 8;  // nb1 ct base
    bf16x8 bbb[2][4];
#pragma unroll
    for (int cf = 0; cf < 4; ++cf)
      bbb[0][cf] = *reinterpret_cast<const bf16x8*>(wp + (size_t)(cf) * 512);

#pragma unroll
    for (int kg = 0; kg < 16; ++kg) {
      const int cur = kg & 1, nxt = cur ^ 1;
      bf16x8 a[4];
#pragma unroll
      for (int t = 0; t < 4; ++t)
        a[t] = *reinterpret_cast<const bf16x8*>(ldsb + ((((tgb + t) * 16 + kg) * 64 + l) << 4));
      if (kg < 15) {
#pragma unroll
        for (int cf = 0; cf < 4; ++cf)
          bbb[nxt][cf] = *reinterpret_cast<const bf16x8*>(wp + (size_t)(kg + 1) * 16384 + cf * 512);
      }
#pragma unroll
      for (int cf = 0; cf < 4; ++cf)
#pragma unroll
        for (int t = 0; t < 4; ++t)
          acc[t][cf] = __builtin_amdgcn_mfma_f32_16x16x32_bf16(a[t], bbb[cur][cf], acc[t][cf], 0, 0, 0);
    }
#pragma unroll
    for (int cf = 0; cf < 4; ++cf)
#pragma unroll
      for (int t = 0; t < 4; ++t)
#pragma unroll
        for (int r = 0; r < 4; ++r)
          partial[t][r] += fast_tanh(acc[t][cf][r] + pqv[4 + cf]) * Vv[4 + cf];
  }

  // reduce over 16 lane_col lanes, then across col-quarter waves via LDS
#pragma unroll
  for (int off = 1; off < 16; off <<= 1)
#pragma unroll
    for (int t = 0; t < 4; ++t)
#pragma unroll
      for (int r = 0; r < 4; ++r) partial[t][r] += __shfl_xor(partial[t][r], off);

  if (lane_col == 0) {
#pragma unroll
    for (int t = 0; t < 4; ++t)
#pragma unroll
      for (int r = 0; r < 4; ++r)
        sbuf[w * 64 + t * 16 + lane_k8 * 4 + r] = partial[t][r];
  }
  __syncthreads();
  if (tid < 128) {                            // row = tid; sum the 4 col-quarters
    int hh = tid >> 6, loc = tid & 63;
    float sc = 0.f;
#pragma unroll
    for (int q = 0; q < 4; ++q) sc += sbuf[(hh * 4 + q) * 64 + loc];
    scoreW[(size_t)b * NS + s0 + tid] = sc;   // bv omitted: softmax shift-invariant
  }
}

// ---- K3: softmax over S per batch -> attention weights (d_out tail) ----
__global__ void softmax_kernel(const float* __restrict__ scoreW, float* __restrict__ attn) {
  int b = blockIdx.x, tid = threadIdx.x;      // 256 threads
  __shared__ float sred[8];
  const float* sc = scoreW + (size_t)b * NS;
  float m = -3.0e38f;
  for (int s = tid; s < NS; s += 256) m = fmaxf(m, sc[s]);
#pragma unroll
  for (int off = 1; off < 64; off <<= 1) m = fmaxf(m, __shfl_xor(m, off));
  if ((tid & 63) == 0) sred[tid >> 6] = m;
  __syncthreads();
  m = fmaxf(fmaxf(sred[0], sred[1]), fmaxf(sred[2], sred[3]));
  float sum = 0.f;
  for (int s = tid; s < NS; s += 256) sum += __expf(sc[s] - m);
#pragma unroll
  for (int off = 1; off < 64; off <<= 1) sum += __shfl_xor(sum, off);
  if ((tid & 63) == 0) sred[4 + (tid >> 6)] = sum;
  __syncthreads();
  float inv = 1.f / (sred[4] + sred[5] + sred[6] + sred[7]);
  float* ab = attn + (size_t)b * NS;
  for (int s = tid; s < NS; s += 256) ab[s] = __expf(sc[s] - m) * inv;
}

// ---- K4: context partials over 256-row chunks ----
__global__ void context_partial_kernel(const float* __restrict__ values,
                                       const float* __restrict__ attn,
                                       float* __restrict__ ctxpart) {
  int blk = blockIdx.x;                       // 32 b * 16 chunks
  int b = blk >> 4, c = blk & 15;
  int tid = threadIdx.x;                      // 256
  int t2 = tid & 127;
  int sg = tid >> 7;
  const float* vb = values + ((size_t)b * NS + c * 256) * ND;
  const float* ab = attn + (size_t)b * NS + c * 256;
  f32x4 acc = {0.f, 0.f, 0.f, 0.f};
  for (int s = sg; s < 256; s += 2) {
    float wv = ab[s];
    f32x4 v = *reinterpret_cast<const f32x4*>(vb + (size_t)s * ND + t2 * 4);
    acc += v * wv;
  }
  __shared__ f32x4 red[128];
  if (sg == 1) red[t2] = acc;
  __syncthreads();
  if (sg == 0) {
    acc += red[t2];
    *reinterpret_cast<f32x4*>(ctxpart + (size_t)blk * ND + t2 * 4) = acc;
  }
}

// ---- K5: reduce chunk partials -> context_vector (d_out head) ----
__global__ void context_reduce_kernel(const float* __restrict__ ctxpart, float* __restrict__ ctx) {
  int b = blockIdx.x, tid = threadIdx.x;      // 128 threads * float4
  f32x4 acc = {0.f, 0.f, 0.f, 0.f};
  for (int c = 0; c < 16; ++c)
    acc += *reinterpret_cast<const f32x4*>(ctxpart + (size_t)(b * 16 + c) * ND + tid * 4);
  *reinterpret_cast<f32x4*>(ctx + (size_t)b * ND + tid * 4) = acc;
}

extern "C" void kernel_launch(void* const* d_in, const int* in_sizes, int n_in,
                              void* d_out, int out_size, void* d_ws, size_t ws_size,
                              hipStream_t stream) {
  const float* query  = (const float*)d_in[0];
  const float* values = (const float*)d_in[1];
  const float* W1     = (const float*)d_in[2];
  const float* b1     = (const float*)d_in[3];
  const float* W2     = (const float*)d_in[4];
  const float* b2     = (const float*)d_in[5];
  const float* V      = (const float*)d_in[6];
  // d_in[7] = bv: softmax-invariant, score not an output: dropped.

  float* ctx_out  = (float*)d_out;            // [32][512]
  float* attn_out = ctx_out + NB * ND;        // [32][4096]

  char* ws = (char*)d_ws;
  __bf16* W1f    = (__bf16*)ws;               // 512 KB
  float*  pq     = (float*)(ws + 524288);     // 64 KB
  float*  scoreW = (float*)(ws + 589824);     // 512 KB
  float*  ctxp   = (float*)(ws + 1114112);    // 1 MB

  hipLaunchKernelGGL(pack_w1_kernel,        dim3(128),     dim3(256), 0, stream, W1, W1f);
  hipLaunchKernelGGL(proj_query_kernel,     dim3(2, NB),   dim3(256), 0, stream, query, W2, b2, b1, pq);
  hipLaunchKernelGGL(score_kernel,          dim3(1024),    dim3(512), 0, stream, values, W1f, pq, V, scoreW);
  hipLaunchKernelGGL(softmax_kernel,        dim3(NB),      dim3(256), 0, stream, scoreW, attn_out);
  hipLaunchKernelGGL(context_partial_kernel,dim3(NB * 16), dim3(256), 0, stream, values, attn_out, ctxp);
  hipLaunchKernelGGL(context_reduce_kernel, dim3(NB),      dim3(128), 0, stream, ctxp, ctx_out);
}